// Round 1
// baseline (55870.197 us; speedup 1.0000x reference)
//
#include <hip/hip_runtime.h>
#include <math.h>

#define Bsz 32768
#define Hd  1024
#define Vn  9
#define Tn  20
#define EOSv 8
#define KFC 784

typedef float f4 __attribute__((ext_vector_type(4)));

// ---------------- init: tok=BOS(0), finished=0, lengths=T ----------------
__global__ __launch_bounds__(256) void k_init(int* __restrict__ tok,
                                              int* __restrict__ fin,
                                              float* __restrict__ lenf) {
    int i = blockIdx.x * 256 + threadIdx.x;
    if (i < Bsz) { tok[i] = 0; fin[i] = 0; lenf[i] = (float)Tn; }
}

// ---------------- h0 = gelu(x @ fc_w^T) ----------------
// C[64x64] per block, BK=16, 256 threads, 4x4 per thread
__global__ __launch_bounds__(256) void k_fc(const float* __restrict__ x,
                                            const float* __restrict__ fcw,
                                            float* __restrict__ h0) {
    __shared__ float As[16][68];
    __shared__ float Ws[16][68];
    const int tid = threadIdx.x;
    const int tx = tid & 15, ty = tid >> 4;
    const int m0 = blockIdx.x * 64, n0 = blockIdx.y * 64;
    const int lrow = tid >> 2, lkc = (tid & 3) << 2;
    float acc[4][4] = {};
    for (int k0 = 0; k0 < KFC; k0 += 16) {
        f4 a = *(const f4*)(x   + (size_t)(m0 + lrow) * KFC + k0 + lkc);
        f4 w = *(const f4*)(fcw + (size_t)(n0 + lrow) * KFC + k0 + lkc);
        #pragma unroll
        for (int q = 0; q < 4; ++q) { As[lkc + q][lrow] = a[q]; Ws[lkc + q][lrow] = w[q]; }
        __syncthreads();
        #pragma unroll
        for (int kk = 0; kk < 16; ++kk) {
            f4 av = *(const f4*)&As[kk][ty * 4];
            f4 wv = *(const f4*)&Ws[kk][tx * 4];
            #pragma unroll
            for (int i = 0; i < 4; ++i)
                #pragma unroll
                for (int j = 0; j < 4; ++j)
                    acc[i][j] = fmaf(av[i], wv[j], acc[i][j]);
        }
        __syncthreads();
    }
    #pragma unroll
    for (int i = 0; i < 4; ++i)
        #pragma unroll
        for (int j = 0; j < 4; ++j) {
            int b = m0 + ty * 4 + i, c = n0 + tx * 4 + j;
            float v = acc[i][j];
            h0[(size_t)b * Hd + c] = 0.5f * v * (1.0f + erff(v * 0.70710678118654752f));
        }
}

// ---------------- one GRU step: h_new = GRU(h, tok) ----------------
// gh = h @ w_hh^T (+b_hh). Block computes 64 rows x 64 cols for all 3 gates.
__global__ __launch_bounds__(256) void k_gru(const float* __restrict__ h,
                                             const float* __restrict__ whh,
                                             const float* __restrict__ wih,
                                             const float* __restrict__ bih,
                                             const float* __restrict__ bhh,
                                             const int* __restrict__ tok,
                                             float* __restrict__ hnew) {
    __shared__ float As[32][68];
    __shared__ float Ws[3][32][68];
    const int tid = threadIdx.x;
    const int tx = tid & 15, ty = tid >> 4;
    const int m0 = blockIdx.x * 64, n0 = blockIdx.y * 64;
    float aR[4][4] = {}, aZ[4][4] = {}, aN[4][4] = {};
    for (int k0 = 0; k0 < Hd; k0 += 32) {
        #pragma unroll
        for (int p = 0; p < 2; ++p) {
            int f = tid + p * 256;
            int r = f >> 3, kc = (f & 7) << 2;
            f4 a = *(const f4*)(h + (size_t)(m0 + r) * Hd + k0 + kc);
            #pragma unroll
            for (int q = 0; q < 4; ++q) As[kc + q][r] = a[q];
        }
        #pragma unroll
        for (int g = 0; g < 3; ++g)
            #pragma unroll
            for (int p = 0; p < 2; ++p) {
                int f = tid + p * 256;
                int r = f >> 3, kc = (f & 7) << 2;
                f4 w = *(const f4*)(whh + (size_t)(g * Hd + n0 + r) * Hd + k0 + kc);
                #pragma unroll
                for (int q = 0; q < 4; ++q) Ws[g][kc + q][r] = w[q];
            }
        __syncthreads();
        #pragma unroll 8
        for (int kk = 0; kk < 32; ++kk) {
            f4 av = *(const f4*)&As[kk][ty * 4];
            f4 wr = *(const f4*)&Ws[0][kk][tx * 4];
            f4 wz = *(const f4*)&Ws[1][kk][tx * 4];
            f4 wn = *(const f4*)&Ws[2][kk][tx * 4];
            #pragma unroll
            for (int i = 0; i < 4; ++i) {
                float a = av[i];
                #pragma unroll
                for (int j = 0; j < 4; ++j) {
                    aR[i][j] = fmaf(a, wr[j], aR[i][j]);
                    aZ[i][j] = fmaf(a, wz[j], aZ[i][j]);
                    aN[i][j] = fmaf(a, wn[j], aN[i][j]);
                }
            }
        }
        __syncthreads();
    }
    #pragma unroll
    for (int i = 0; i < 4; ++i) {
        const int b = m0 + ty * 4 + i;
        const int tk = tok[b];
        #pragma unroll
        for (int j = 0; j < 4; ++j) {
            const int c = n0 + tx * 4 + j;
            float gir = wih[(size_t)c * Vn + tk] + bih[c];
            float giz = wih[(size_t)(Hd + c) * Vn + tk] + bih[Hd + c];
            float gin = wih[(size_t)(2 * Hd + c) * Vn + tk] + bih[2 * Hd + c];
            float ghr = aR[i][j] + bhh[c];
            float ghz = aZ[i][j] + bhh[Hd + c];
            float ghn = aN[i][j] + bhh[2 * Hd + c];
            float r = 1.0f / (1.0f + expf(-(gir + ghr)));
            float z = 1.0f / (1.0f + expf(-(giz + ghz)));
            float n = tanhf(gin + r * ghn);
            float hold = h[(size_t)b * Hd + c];
            hnew[(size_t)b * Hd + c] = (1.0f - z) * n + z * hold;
        }
    }
}

// ---------------- logits + gumbel argmax + one-hot + EOS ----------------
// one wave per row; 4 rows per 256-thread block
__global__ __launch_bounds__(256) void k_out(const float* __restrict__ hnew,
                                             const float* __restrict__ pw,
                                             const float* __restrict__ pb,
                                             const float* __restrict__ gum,
                                             const float* __restrict__ tau,
                                             float* __restrict__ msg,
                                             float* __restrict__ lenf,
                                             int* __restrict__ tok,
                                             int* __restrict__ fin,
                                             int t) {
    const int lane = threadIdx.x & 63;
    const int wv = threadIdx.x >> 6;
    const int b = blockIdx.x * 4 + wv;
    const float* hr = hnew + (size_t)b * Hd;
    float s[Vn] = {};
    #pragma unroll
    for (int c0 = 0; c0 < 16; c0 += 4) {
        f4 hv = *(const f4*)(hr + lane * 16 + c0);
        #pragma unroll
        for (int v = 0; v < Vn; ++v) {
            f4 pv = *(const f4*)(pw + (size_t)v * Hd + lane * 16 + c0);
            #pragma unroll
            for (int q = 0; q < 4; ++q) s[v] = fmaf(hv[q], pv[q], s[v]);
        }
    }
    #pragma unroll
    for (int v = 0; v < Vn; ++v)
        #pragma unroll
        for (int off = 32; off > 0; off >>= 1)
            s[v] += __shfl_xor(s[v], off, 64);
    if (lane == 0) {
        const float tv = tau[0];
        float zv[Vn];
        #pragma unroll
        for (int v = 0; v < Vn; ++v)
            zv[v] = (s[v] + pb[v] + gum[(size_t)b * Vn + v]) / tv;
        int idx = 0; float m = zv[0];
        #pragma unroll
        for (int v = 1; v < Vn; ++v)
            if (zv[v] > m) { m = zv[v]; idx = v; }
        float* orow = msg + ((size_t)b * Tn + t) * Vn;
        #pragma unroll
        for (int v = 0; v < Vn; ++v) orow[v] = (v == idx) ? 1.0f : 0.0f;
        tok[b] = idx;
        if (idx == EOSv && fin[b] == 0) { fin[b] = 1; lenf[b] = (float)(t + 1); }
    }
}

extern "C" void kernel_launch(void* const* d_in, const int* in_sizes, int n_in,
                              void* d_out, int out_size, void* d_ws, size_t ws_size,
                              hipStream_t stream) {
    const float* x   = (const float*)d_in[0];
    const float* tau = (const float*)d_in[1];
    const float* fcw = (const float*)d_in[2];
    const float* wih = (const float*)d_in[3];
    const float* whh = (const float*)d_in[4];
    const float* bih = (const float*)d_in[5];
    const float* bhh = (const float*)d_in[6];
    const float* pw  = (const float*)d_in[7];
    const float* pb  = (const float*)d_in[8];
    const float* gum = (const float*)d_in[9];

    float* msg  = (float*)d_out;
    float* lenf = msg + (size_t)Bsz * Tn * Vn;

    float* hA = (float*)d_ws;
    float* hB = hA + (size_t)Bsz * Hd;
    int* tok  = (int*)(hB + (size_t)Bsz * Hd);
    int* fin  = tok + Bsz;

    k_init<<<Bsz / 256, 256, 0, stream>>>(tok, fin, lenf);
    k_fc<<<dim3(Bsz / 64, Hd / 64), 256, 0, stream>>>(x, fcw, hA);
    for (int t = 0; t < Tn; ++t) {
        k_gru<<<dim3(Bsz / 64, Hd / 64), 256, 0, stream>>>(hA, whh, wih, bih, bhh, tok, hB);
        k_out<<<Bsz / 4, 256, 0, stream>>>(hB, pw, pb, gum + (size_t)t * Bsz * Vn,
                                           tau, msg, lenf, tok, fin, t);
        float* tmp = hA; hA = hB; hB = tmp;
    }
}

// Round 3
// 28051.920 us; speedup vs baseline: 1.9917x; 1.9917x over previous
//
#include <hip/hip_runtime.h>
#include <math.h>

#define Bsz 32768
#define Hd  1024
#define Vn  9
#define Tn  20
#define EOSv 8
#define KFC 784

typedef float f4 __attribute__((ext_vector_type(4)));
typedef float f32x16 __attribute__((ext_vector_type(16)));
typedef short short8 __attribute__((ext_vector_type(8)));
typedef unsigned short us8v __attribute__((ext_vector_type(8)));

__device__ __forceinline__ unsigned short bf_rne(float x) {
    unsigned u = __float_as_uint(x);
    return (unsigned short)((u + 0x7fffu + ((u >> 16) & 1u)) >> 16);
}
__device__ __forceinline__ float bf_val(unsigned short h) {
    return __uint_as_float(((unsigned)h) << 16);
}

// ---------------- init: st = tok|fin packed, lengths=T ----------------
__global__ __launch_bounds__(256) void k_init(int* __restrict__ st,
                                              float* __restrict__ lenf) {
    int i = blockIdx.x * 256 + threadIdx.x;
    if (i < Bsz) { st[i] = 0; lenf[i] = (float)Tn; }
}

// ---------------- giTab[tk][n] = w_ih[n][tk] + b_ih[n]  (9 x 3072) ----------------
__global__ __launch_bounds__(256) void k_prep(const float* __restrict__ wih,
                                              const float* __restrict__ bih,
                                              float* __restrict__ giTab) {
    int i = blockIdx.x * 256 + threadIdx.x;   // < 9*3072 = 27648
    int tk = i / 3072, n = i - tk * 3072;
    giTab[i] = wih[(size_t)n * Vn + tk] + bih[n];
}

// ---------------- h0 = gelu(x @ fc_w^T) ----------------
__global__ __launch_bounds__(256) void k_fc(const float* __restrict__ x,
                                            const float* __restrict__ fcw,
                                            float* __restrict__ h0) {
    __shared__ float As[16][68];
    __shared__ float Ws[16][68];
    const int tid = threadIdx.x;
    const int tx = tid & 15, ty = tid >> 4;
    const int m0 = blockIdx.x * 64, n0 = blockIdx.y * 64;
    const int lrow = tid >> 2, lkc = (tid & 3) << 2;
    float acc[4][4] = {};
    for (int k0 = 0; k0 < KFC; k0 += 16) {
        f4 a = *(const f4*)(x   + (size_t)(m0 + lrow) * KFC + k0 + lkc);
        f4 w = *(const f4*)(fcw + (size_t)(n0 + lrow) * KFC + k0 + lkc);
        #pragma unroll
        for (int q = 0; q < 4; ++q) { As[lkc + q][lrow] = a[q]; Ws[lkc + q][lrow] = w[q]; }
        __syncthreads();
        #pragma unroll
        for (int kk = 0; kk < 16; ++kk) {
            f4 av = *(const f4*)&As[kk][ty * 4];
            f4 wv = *(const f4*)&Ws[kk][tx * 4];
            #pragma unroll
            for (int i = 0; i < 4; ++i)
                #pragma unroll
                for (int j = 0; j < 4; ++j)
                    acc[i][j] = fmaf(av[i], wv[j], acc[i][j]);
        }
        __syncthreads();
    }
    #pragma unroll
    for (int i = 0; i < 4; ++i)
        #pragma unroll
        for (int j = 0; j < 4; ++j) {
            int b = m0 + ty * 4 + i, c = n0 + tx * 4 + j;
            float v = acc[i][j];
            h0[(size_t)b * Hd + c] = 0.5f * v * (1.0f + erff(v * 0.70710678118654752f));
        }
}

// ---------------- fused GRU step: hdst = GRU(hsrc, tok) via bf16x3 MFMA ----------------
// block tile: 128 rows x 64 h-cols x 3 gates; 4 waves (2m x 2n); wave: 64 rows,
// 32 cols, 3 gate-ntiles. A and B split3'd on the fly into LDS. BK=32.
__global__ __launch_bounds__(256, 2) void k_step(
        const float* __restrict__ hsrc, float* __restrict__ hdst,
        const float* __restrict__ whh, const float* __restrict__ bhh,
        const float* __restrict__ giTab, int* __restrict__ st) {
    __shared__ unsigned short Asm[3 * 4 * 128 * 8];      // 24576 B
    __shared__ unsigned short Bsm[3 * 4 * 196 * 8];      // 37632 B (stride 196 pads banks)
    const int tid = threadIdx.x;
    const int lane = tid & 63, wid = tid >> 6;
    const int wm = wid >> 1, wn = wid & 1;
    const int l31 = lane & 31, lh = lane >> 5;

    // XCD-bijective swizzle: all 16 col-groups of a row-block on one XCD
    const int w = blockIdx.x;
    const int rb = (w & 7) * 32 + ((w >> 3) >> 4);   // 0..255
    const int cg = (w >> 3) & 15;                    // 0..15
    const int m_blk = rb * 128;
    const int c0 = cg * 64;

    f32x16 acc[2][3];
    #pragma unroll
    for (int mt = 0; mt < 2; ++mt)
        #pragma unroll
        for (int g = 0; g < 3; ++g)
            #pragma unroll
            for (int e = 0; e < 16; ++e) acc[mt][g][e] = 0.0f;

    const int ar = tid >> 1, ak = (tid & 1) << 4;    // A: row, k-offset(16)
    const int br_ = tid >> 2, bkq = tid & 3;         // B: row-of-192(per j), kq

    f4 pa[4];
    f4 pb[3][2];

    auto load_regs = [&](int s) {
        const int k0 = s << 5;
        const float* ap = hsrc + (size_t)(m_blk + ar) * Hd + (k0 + ak);
        pa[0] = *(const f4*)(ap);
        pa[1] = *(const f4*)(ap + 4);
        pa[2] = *(const f4*)(ap + 8);
        pa[3] = *(const f4*)(ap + 12);
        #pragma unroll
        for (int j = 0; j < 3; ++j) {
            int r192 = j * 64 + br_;
            int g = r192 >> 6, c = r192 & 63;
            const float* bp = whh + (size_t)(g * Hd + c0 + c) * Hd + (k0 + (bkq << 3));
            pb[j][0] = *(const f4*)(bp);
            pb[j][1] = *(const f4*)(bp + 4);
        }
    };

    auto write_lds = [&]() {
        #pragma unroll
        for (int half = 0; half < 2; ++half) {
            const int kq = ((tid & 1) << 1) + half;
            us8v o0, o1, o2;
            #pragma unroll
            for (int e = 0; e < 8; ++e) {
                float x = pa[half * 2 + (e >> 2)][e & 3];
                unsigned short s0 = bf_rne(x);
                float r = x - bf_val(s0);
                unsigned short s1 = bf_rne(r);
                o0[e] = s0; o1[e] = s1; o2[e] = bf_rne(r - bf_val(s1));
            }
            *(us8v*)&Asm[((0 * 4 + kq) * 128 + ar) * 8] = o0;
            *(us8v*)&Asm[((1 * 4 + kq) * 128 + ar) * 8] = o1;
            *(us8v*)&Asm[((2 * 4 + kq) * 128 + ar) * 8] = o2;
        }
        #pragma unroll
        for (int j = 0; j < 3; ++j) {
            const int r192 = j * 64 + br_;
            us8v o0, o1, o2;
            #pragma unroll
            for (int e = 0; e < 8; ++e) {
                float x = pb[j][e >> 2][e & 3];
                unsigned short s0 = bf_rne(x);
                float r = x - bf_val(s0);
                unsigned short s1 = bf_rne(r);
                o0[e] = s0; o1[e] = s1; o2[e] = bf_rne(r - bf_val(s1));
            }
            *(us8v*)&Bsm[((0 * 4 + bkq) * 196 + r192) * 8] = o0;
            *(us8v*)&Bsm[((1 * 4 + bkq) * 196 + r192) * 8] = o1;
            *(us8v*)&Bsm[((2 * 4 + bkq) * 196 + r192) * 8] = o2;
        }
    };

    load_regs(0);
    for (int s = 0; s < 32; ++s) {
        __syncthreads();
        write_lds();
        __syncthreads();
        if (s < 31) load_regs(s + 1);   // prefetch hides under MFMA below
        #pragma unroll
        for (int kc = 0; kc < 2; ++kc) {
            const int kq = (kc << 1) + lh;
            short8 af[2][3];
            #pragma unroll
            for (int mt = 0; mt < 2; ++mt)
                #pragma unroll
                for (int p = 0; p < 3; ++p)
                    af[mt][p] = *(const short8*)&Asm[((p * 4 + kq) * 128 + wm * 64 + mt * 32 + l31) * 8];
            short8 bf[3][3];
            #pragma unroll
            for (int nt = 0; nt < 3; ++nt)
                #pragma unroll
                for (int p = 0; p < 3; ++p)
                    bf[nt][p] = *(const short8*)&Bsm[((p * 4 + kq) * 196 + nt * 64 + wn * 32 + l31) * 8];
            #pragma unroll
            for (int mt = 0; mt < 2; ++mt)
                #pragma unroll
                for (int nt = 0; nt < 3; ++nt) {
                    f32x16 c = acc[mt][nt];
                    c = __builtin_amdgcn_mfma_f32_32x32x16_bf16(af[mt][2], bf[nt][0], c, 0, 0, 0);
                    c = __builtin_amdgcn_mfma_f32_32x32x16_bf16(af[mt][1], bf[nt][1], c, 0, 0, 0);
                    c = __builtin_amdgcn_mfma_f32_32x32x16_bf16(af[mt][0], bf[nt][2], c, 0, 0, 0);
                    c = __builtin_amdgcn_mfma_f32_32x32x16_bf16(af[mt][1], bf[nt][0], c, 0, 0, 0);
                    c = __builtin_amdgcn_mfma_f32_32x32x16_bf16(af[mt][0], bf[nt][1], c, 0, 0, 0);
                    c = __builtin_amdgcn_mfma_f32_32x32x16_bf16(af[mt][0], bf[nt][0], c, 0, 0, 0);
                    acc[mt][nt] = c;
                }
        }
    }

    // fused GRU epilogue (wave-local: acc[mt][{r,z,n}] share (row,col))
    const int col = c0 + wn * 32 + l31;
    const float bhr = bhh[col], bhz = bhh[Hd + col], bhn = bhh[2 * Hd + col];
    #pragma unroll
    for (int mt = 0; mt < 2; ++mt) {
        #pragma unroll
        for (int reg = 0; reg < 16; ++reg) {
            const int row = m_blk + wm * 64 + mt * 32 + 4 * lh + (reg & 3) + 8 * (reg >> 2);
            const int tk = st[row] & 15;
            const float* gi = giTab + tk * 3072;
            float rr = 1.0f / (1.0f + expf(-(gi[col] + acc[mt][0][reg] + bhr)));
            float zz = 1.0f / (1.0f + expf(-(gi[Hd + col] + acc[mt][1][reg] + bhz)));
            float nn = tanhf(gi[2 * Hd + col] + rr * (acc[mt][2][reg] + bhn));
            float hold = hsrc[(size_t)row * Hd + col];
            hdst[(size_t)row * Hd + col] = (1.0f - zz) * nn + zz * hold;
        }
    }
}

// ---------------- logits + gumbel argmax + one-hot + EOS ----------------
__global__ __launch_bounds__(256) void k_proj(const float* __restrict__ hnew,
        const float* __restrict__ pw, const float* __restrict__ pb,
        const float* __restrict__ gum, const float* __restrict__ tau,
        float* __restrict__ msg, float* __restrict__ lenf,
        int* __restrict__ st, int t) {
    const int lane = threadIdx.x & 63;
    const int wv = threadIdx.x >> 6;
    const int b = blockIdx.x * 4 + wv;
    const float* hr = hnew + (size_t)b * Hd;
    float s[Vn] = {};
    #pragma unroll
    for (int c0 = 0; c0 < 16; c0 += 4) {
        f4 hv = *(const f4*)(hr + lane * 16 + c0);
        #pragma unroll
        for (int v = 0; v < Vn; ++v) {
            f4 pv = *(const f4*)(pw + (size_t)v * Hd + lane * 16 + c0);
            #pragma unroll
            for (int q = 0; q < 4; ++q) s[v] = fmaf(hv[q], pv[q], s[v]);
        }
    }
    #pragma unroll
    for (int v = 0; v < Vn; ++v)
        #pragma unroll
        for (int off = 32; off > 0; off >>= 1)
            s[v] += __shfl_xor(s[v], off, 64);
    if (lane == 0) {
        const float tv = tau[0];
        float zv[Vn];
        #pragma unroll
        for (int v = 0; v < Vn; ++v)
            zv[v] = (s[v] + pb[v] + gum[(size_t)b * Vn + v]) / tv;
        int idx = 0; float m = zv[0];
        #pragma unroll
        for (int v = 1; v < Vn; ++v)
            if (zv[v] > m) { m = zv[v]; idx = v; }
        float* orow = msg + ((size_t)b * Tn + t) * Vn;
        #pragma unroll
        for (int v = 0; v < Vn; ++v) orow[v] = (v == idx) ? 1.0f : 0.0f;
        const int old = st[b];
        const int fn = old >> 4;
        st[b] = idx | (((fn != 0) || (idx == EOSv)) ? 16 : 0);
        if (idx == EOSv && fn == 0) lenf[b] = (float)(t + 1);
    }
}

extern "C" void kernel_launch(void* const* d_in, const int* in_sizes, int n_in,
                              void* d_out, int out_size, void* d_ws, size_t ws_size,
                              hipStream_t stream) {
    const float* x   = (const float*)d_in[0];
    const float* tau = (const float*)d_in[1];
    const float* fcw = (const float*)d_in[2];
    const float* wih = (const float*)d_in[3];
    const float* whh = (const float*)d_in[4];
    const float* bih = (const float*)d_in[5];
    const float* bhh = (const float*)d_in[6];
    const float* pw  = (const float*)d_in[7];
    const float* pb  = (const float*)d_in[8];
    const float* gum = (const float*)d_in[9];

    float* msg  = (float*)d_out;
    float* lenf = msg + (size_t)Bsz * Tn * Vn;

    // workspace: 268,677,120 B total (< round-1-proven 268,697,600)
    char* ws = (char*)d_ws;
    float* hA    = (float*)ws;                         // 134,217,728
    float* hB    = (float*)(ws + 134217728ull);        // 134,217,728
    float* giTab = (float*)(ws + 268435456ull);        //     110,592
    int*   st    = (int*)  (ws + 268546048ull);        //     131,072

    k_init<<<Bsz / 256, 256, 0, stream>>>(st, lenf);
    k_prep<<<108, 256, 0, stream>>>(wih, bih, giTab);
    k_fc<<<dim3(Bsz / 64, Hd / 64), 256, 0, stream>>>(x, fcw, hA);
    for (int t = 0; t < Tn; ++t) {
        const float* src = (t & 1) ? hB : hA;
        float*       dst = (t & 1) ? hA : hB;
        k_step<<<4096, 256, 0, stream>>>(src, dst, whh, bhh, giTab, st);
        k_proj<<<Bsz / 4, 256, 0, stream>>>(dst, pw, pb, gum + (size_t)t * Bsz * Vn,
                                            tau, msg, lenf, st, t);
    }
}

// Round 4
// 26112.967 us; speedup vs baseline: 2.1396x; 1.0743x over previous
//
#include <hip/hip_runtime.h>
#include <math.h>

#define Bsz 32768
#define Hd  1024
#define Vn  9
#define Tn  20
#define EOSv 8
#define KFC 784

typedef float f4 __attribute__((ext_vector_type(4)));
typedef float f32x16 __attribute__((ext_vector_type(16)));
typedef short short8 __attribute__((ext_vector_type(8)));
typedef unsigned short us4 __attribute__((ext_vector_type(4)));
typedef unsigned short us8v __attribute__((ext_vector_type(8)));

__device__ __forceinline__ unsigned short bf_rne(float x) {
    unsigned u = __float_as_uint(x);
    return (unsigned short)((u + 0x7fffu + ((u >> 16) & 1u)) >> 16);
}
__device__ __forceinline__ float bf_val(unsigned short h) {
    return __uint_as_float(((unsigned)h) << 16);
}
__device__ __forceinline__ void split3(float x, unsigned short& p0, unsigned short& p1, unsigned short& p2) {
    p0 = bf_rne(x); float r = x - bf_val(p0);
    p1 = bf_rne(r); r -= bf_val(p1);
    p2 = bf_rne(r);
}
__device__ __forceinline__ int slotr(int r) { return r ^ ((r >> 3) & 3); }

// ---------------- init ----------------
__global__ __launch_bounds__(256) void k_init(int* __restrict__ st,
                                              float* __restrict__ lenf) {
    int i = blockIdx.x * 256 + threadIdx.x;
    if (i < Bsz) { st[i] = 0; lenf[i] = (float)Tn; }
}

// ---------------- giTab[tk][n] = w_ih[n][tk] + b_ih[n] ----------------
__global__ __launch_bounds__(256) void k_prep(const float* __restrict__ wih,
                                              const float* __restrict__ bih,
                                              float* __restrict__ giTab) {
    int i = blockIdx.x * 256 + threadIdx.x;
    int tk = i / 3072, n = i - tk * 3072;
    giTab[i] = wih[(size_t)n * Vn + tk] + bih[n];
}

// ---------------- w_hh -> pre-tiled bf16x3 planes (fragment order) ----------------
// unit u = ((ct*64 + kc16)*3 + p): lane l holds B[k][n], n = ct*32+(l&31),
// k = kc16*16 + (l>>5)*8 + i   (matches k_step's MFMA B-fragment exactly)
__global__ __launch_bounds__(256) void k_prepB(const float* __restrict__ whh,
                                               unsigned short* __restrict__ wp) {
    int g = blockIdx.x * 256 + threadIdx.x;
    int lane = g & 63, u = g >> 6;
    int p = u % 3, kc = (u / 3) & 63, ct = u / 192;
    int col = ct * 32 + (lane & 31);
    int k = kc * 16 + (lane >> 5) * 8;
    const float* src = whh + (size_t)col * Hd + k;
    unsigned short v[8];
    #pragma unroll
    for (int i = 0; i < 8; ++i) {
        unsigned short s0, s1, s2; split3(src[i], s0, s1, s2);
        v[i] = (p == 0) ? s0 : ((p == 1) ? s1 : s2);
    }
    unsigned short* dst = wp + (size_t)u * 512 + lane * 8;
    us4 w0; w0[0]=v[0]; w0[1]=v[1]; w0[2]=v[2]; w0[3]=v[3];
    us4 w1; w1[0]=v[4]; w1[1]=v[5]; w1[2]=v[6]; w1[3]=v[7];
    *(us4*)dst = w0;
    *(us4*)(dst + 4) = w1;
}

// ---------------- h0 = gelu(x @ fc_w^T) ----------------
__global__ __launch_bounds__(256) void k_fc(const float* __restrict__ x,
                                            const float* __restrict__ fcw,
                                            float* __restrict__ h0) {
    __shared__ float As[16][68];
    __shared__ float Ws[16][68];
    const int tid = threadIdx.x;
    const int tx = tid & 15, ty = tid >> 4;
    const int m0 = blockIdx.x * 64, n0 = blockIdx.y * 64;
    const int lrow = tid >> 2, lkc = (tid & 3) << 2;
    float acc[4][4] = {};
    for (int k0 = 0; k0 < KFC; k0 += 16) {
        f4 a = *(const f4*)(x   + (size_t)(m0 + lrow) * KFC + k0 + lkc);
        f4 w = *(const f4*)(fcw + (size_t)(n0 + lrow) * KFC + k0 + lkc);
        #pragma unroll
        for (int q = 0; q < 4; ++q) { As[lkc + q][lrow] = a[q]; Ws[lkc + q][lrow] = w[q]; }
        __syncthreads();
        #pragma unroll
        for (int kk = 0; kk < 16; ++kk) {
            f4 av = *(const f4*)&As[kk][ty * 4];
            f4 wv = *(const f4*)&Ws[kk][tx * 4];
            #pragma unroll
            for (int i = 0; i < 4; ++i)
                #pragma unroll
                for (int j = 0; j < 4; ++j)
                    acc[i][j] = fmaf(av[i], wv[j], acc[i][j]);
        }
        __syncthreads();
    }
    #pragma unroll
    for (int i = 0; i < 4; ++i)
        #pragma unroll
        for (int j = 0; j < 4; ++j) {
            int b = m0 + ty * 4 + i, c = n0 + tx * 4 + j;
            float v = acc[i][j];
            h0[(size_t)b * Hd + c] = 0.5f * v * (1.0f + erff(v * 0.70710678118654752f));
        }
}

// ---------------- fused GRU step (bf16x3 MFMA, B pre-tiled, A dbuf LDS) ----------------
// block: 128 rows x 64 h-cols x 3 gates; 4 waves 2m x 2n; wave 64r x 32c x 3g
__global__ __launch_bounds__(256, 2) void k_step(
        const float* __restrict__ hsrc, float* __restrict__ hdst,
        const unsigned short* __restrict__ wp, const float* __restrict__ bhh,
        const float* __restrict__ giTab, const int* __restrict__ st) {
    __shared__ unsigned short Asm[2][3 * 4 * 128 * 8];   // 2 x 24576 B
    const int tid = threadIdx.x;
    const int lane = tid & 63, wid = tid >> 6;
    const int wm = wid >> 1, wn = wid & 1;
    const int l31 = lane & 31, lh = lane >> 5;

    const int w = blockIdx.x;
    const int rb = (w & 7) * 32 + ((w >> 3) >> 4);
    const int cg = (w >> 3) & 15;
    const int m_blk = rb * 128;
    const int c0 = cg * 64;

    f32x16 acc[2][3];
    #pragma unroll
    for (int mt = 0; mt < 2; ++mt)
        #pragma unroll
        for (int g = 0; g < 3; ++g)
            #pragma unroll
            for (int e = 0; e < 16; ++e) acc[mt][g][e] = 0.0f;

    // A staging geometry: thread -> row ar, k-half (16 of the 32-chunk)
    const int ar = tid >> 1;
    const int kqw = (tid & 1) << 1;
    const int wslot = slotr(ar);
    int rslot[2];
    #pragma unroll
    for (int mt = 0; mt < 2; ++mt) rslot[mt] = slotr(wm * 64 + mt * 32 + l31);

    // B fragment base pointers (pre-tiled wp), per gate
    const unsigned short* bg[3];
    #pragma unroll
    for (int g = 0; g < 3; ++g) {
        int ct = g * 32 + cg * 2 + wn;
        bg[g] = wp + (size_t)ct * 64 * 3 * 512 + (size_t)lane * 8;
    }

    f4 pa[4];
    auto load_a = [&](int s) {
        const float* ap = hsrc + (size_t)(m_blk + ar) * Hd + (s << 5) + ((tid & 1) << 4);
        pa[0] = *(const f4*)(ap);
        pa[1] = *(const f4*)(ap + 4);
        pa[2] = *(const f4*)(ap + 8);
        pa[3] = *(const f4*)(ap + 12);
    };
    auto write_a = [&](int bufi) {
        #pragma unroll
        for (int half = 0; half < 2; ++half) {
            const int kq = kqw + half;
            us8v o0, o1, o2;
            #pragma unroll
            for (int e = 0; e < 8; ++e) {
                float x = pa[half * 2 + (e >> 2)][e & 3];
                unsigned short s0 = bf_rne(x);
                float r = x - bf_val(s0);
                unsigned short s1 = bf_rne(r);
                o0[e] = s0; o1[e] = s1; o2[e] = bf_rne(r - bf_val(s1));
            }
            *(us8v*)&Asm[bufi][((0 * 4 + kq) * 128 + wslot) * 8] = o0;
            *(us8v*)&Asm[bufi][((1 * 4 + kq) * 128 + wslot) * 8] = o1;
            *(us8v*)&Asm[bufi][((2 * 4 + kq) * 128 + wslot) * 8] = o2;
        }
    };

    load_a(0);
    write_a(0);
    load_a(1);
    __syncthreads();

    for (int s = 0; s < 32; ++s) {
        const int bi = s & 1;
        if (s < 31) write_a(bi ^ 1);   // stage s+1 (VALU+LDS, hides under MFMA)
        if (s < 30) load_a(s + 2);     // prefetch s+2 (VMEM, hides under MFMA)
        #pragma unroll
        for (int kc = 0; kc < 2; ++kc) {
            const int kq = (kc << 1) + lh;
            short8 af[2][3];
            #pragma unroll
            for (int mt = 0; mt < 2; ++mt)
                #pragma unroll
                for (int p = 0; p < 3; ++p)
                    af[mt][p] = *(const short8*)&Asm[bi][((p * 4 + kq) * 128 + rslot[mt]) * 8];
            #pragma unroll
            for (int g = 0; g < 3; ++g) {
                const unsigned short* bp = bg[g] + ((size_t)(s * 2 + kc) * 3) * 512;
                short8 b0 = *(const short8*)(bp);
                short8 b1 = *(const short8*)(bp + 512);
                short8 b2 = *(const short8*)(bp + 1024);
                #pragma unroll
                for (int mt = 0; mt < 2; ++mt) {
                    f32x16 c = acc[mt][g];
                    c = __builtin_amdgcn_mfma_f32_32x32x16_bf16(af[mt][2], b0, c, 0, 0, 0);
                    c = __builtin_amdgcn_mfma_f32_32x32x16_bf16(af[mt][1], b1, c, 0, 0, 0);
                    c = __builtin_amdgcn_mfma_f32_32x32x16_bf16(af[mt][0], b2, c, 0, 0, 0);
                    c = __builtin_amdgcn_mfma_f32_32x32x16_bf16(af[mt][1], b0, c, 0, 0, 0);
                    c = __builtin_amdgcn_mfma_f32_32x32x16_bf16(af[mt][0], b1, c, 0, 0, 0);
                    c = __builtin_amdgcn_mfma_f32_32x32x16_bf16(af[mt][0], b0, c, 0, 0, 0);
                    acc[mt][g] = c;
                }
            }
        }
        __syncthreads();
    }

    // fused GRU epilogue (wave-local: acc[mt][{r,z,n}] share (row,col))
    const int col = c0 + wn * 32 + l31;
    const float bhr = bhh[col], bhz = bhh[Hd + col], bhn = bhh[2 * Hd + col];
    #pragma unroll
    for (int mt = 0; mt < 2; ++mt) {
        #pragma unroll
        for (int reg = 0; reg < 16; ++reg) {
            const int row = m_blk + wm * 64 + mt * 32 + 4 * lh + (reg & 3) + 8 * (reg >> 2);
            const int tk = st[row] & 15;
            const float* gi = giTab + tk * 3072;
            float rr = 1.0f / (1.0f + expf(-(gi[col] + acc[mt][0][reg] + bhr)));
            float zz = 1.0f / (1.0f + expf(-(gi[Hd + col] + acc[mt][1][reg] + bhz)));
            float nn = tanhf(gi[2 * Hd + col] + rr * (acc[mt][2][reg] + bhn));
            float hold = hsrc[(size_t)row * Hd + col];
            hdst[(size_t)row * Hd + col] = (1.0f - zz) * nn + zz * hold;
        }
    }
}

// ---------------- logits + gumbel argmax + one-hot + EOS ----------------
__global__ __launch_bounds__(256) void k_proj(const float* __restrict__ hnew,
        const float* __restrict__ pw, const float* __restrict__ pb,
        const float* __restrict__ gum, const float* __restrict__ tau,
        float* __restrict__ msg, float* __restrict__ lenf,
        int* __restrict__ st, int t) {
    const int lane = threadIdx.x & 63;
    const int wv = threadIdx.x >> 6;
    const int b = blockIdx.x * 4 + wv;
    const float* hr = hnew + (size_t)b * Hd;
    float s[Vn] = {};
    #pragma unroll
    for (int c0 = 0; c0 < 16; c0 += 4) {
        f4 hv = *(const f4*)(hr + lane * 16 + c0);
        #pragma unroll
        for (int v = 0; v < Vn; ++v) {
            f4 pv = *(const f4*)(pw + (size_t)v * Hd + lane * 16 + c0);
            #pragma unroll
            for (int q = 0; q < 4; ++q) s[v] = fmaf(hv[q], pv[q], s[v]);
        }
    }
    #pragma unroll
    for (int v = 0; v < Vn; ++v)
        #pragma unroll
        for (int off = 32; off > 0; off >>= 1)
            s[v] += __shfl_xor(s[v], off, 64);
    if (lane == 0) {
        const float tv = tau[0];
        float zv[Vn];
        #pragma unroll
        for (int v = 0; v < Vn; ++v)
            zv[v] = (s[v] + pb[v] + gum[(size_t)b * Vn + v]) / tv;
        int idx = 0; float m = zv[0];
        #pragma unroll
        for (int v = 1; v < Vn; ++v)
            if (zv[v] > m) { m = zv[v]; idx = v; }
        float* orow = msg + ((size_t)b * Tn + t) * Vn;
        #pragma unroll
        for (int v = 0; v < Vn; ++v) orow[v] = (v == idx) ? 1.0f : 0.0f;
        const int old = st[b];
        const int fn = old >> 4;
        st[b] = idx | (((fn != 0) || (idx == EOSv)) ? 16 : 0);
        if (idx == EOSv && fn == 0) lenf[b] = (float)(t + 1);
    }
}

extern "C" void kernel_launch(void* const* d_in, const int* in_sizes, int n_in,
                              void* d_out, int out_size, void* d_ws, size_t ws_size,
                              hipStream_t stream) {
    const float* x   = (const float*)d_in[0];
    const float* tau = (const float*)d_in[1];
    const float* fcw = (const float*)d_in[2];
    const float* wih = (const float*)d_in[3];
    const float* whh = (const float*)d_in[4];
    const float* bhh = (const float*)d_in[6];
    const float* bih = (const float*)d_in[5];
    const float* pw  = (const float*)d_in[7];
    const float* pb  = (const float*)d_in[8];
    const float* gum = (const float*)d_in[9];

    float* msg  = (float*)d_out;
    float* lenf = msg + (size_t)Bsz * Tn * Vn;

    // workspace: 287,551,488 B
    char* ws = (char*)d_ws;
    float*          hA    = (float*)ws;                          // 134,217,728
    float*          hB    = (float*)(ws + 134217728ull);         // 134,217,728
    unsigned short* wp    = (unsigned short*)(ws + 268435456ull);//  18,874,368
    float*          giTab = (float*)(ws + 287309824ull);         //     110,592
    int*            st    = (int*)  (ws + 287420416ull);         //     131,072

    k_init<<<Bsz / 256, 256, 0, stream>>>(st, lenf);
    k_prep<<<108, 256, 0, stream>>>(wih, bih, giTab);
    k_prepB<<<4608, 256, 0, stream>>>(whh, wp);
    k_fc<<<dim3(Bsz / 64, Hd / 64), 256, 0, stream>>>(x, fcw, hA);
    for (int t = 0; t < Tn; ++t) {
        const float* src = (t & 1) ? hB : hA;
        float*       dst = (t & 1) ? hA : hB;
        k_step<<<4096, 256, 0, stream>>>(src, dst, wp, bhh, giTab, st);
        k_proj<<<Bsz / 4, 256, 0, stream>>>(dst, pw, pb, gum + (size_t)t * Bsz * Vn,
                                            tau, msg, lenf, st, t);
    }
}